// Round 18
// baseline (51.990 us; speedup 1.0000x reference)
//
#include <hip/hip_runtime.h>
#include <hip/hip_bf16.h>
#include <stdint.h>

// out[b,o,p] = sum_{r,c} mat0[b,c,p] * mat1[o,c,r]*Alpha[r] * mask[r,p]
// GEMM: M=256 (o), N=32768 (n=b*4096+p), K=2048 (k=c*8+r).
// A[o,k] = mat1[o,c,r]*Alpha[r]  (prepped FP16 in d_ws, layout [c][o][8r])
// B[k,n] = mat0[b,c,p]*mask[r,p] synthesized IN REGISTERS per lane (fp16).
// Round 18 = R17 + order-robust vmcnt(0) waits (R17's counted vmcnt(16)
// assumed FIFO order [stages, P-loads]; the compiler can hoist pure P loads
// above the global_load_lds builtins, leaving stage DMAs un-drained ->
// slab read before landing -> NaN). vmcnt(0) per half-round is R14's
// proven-correct skeleton. Wave = 32x128: each A-fragment read from LDS
// exactly ONCE (4 ds_read/wave-round; LDS 96->64KB/CU-round). 4-slab ring,
// pointer-bump P (folded immediates), read-ahead, barrier per 2 rounds.

typedef __attribute__((ext_vector_type(8)))  _Float16 half8;
typedef __attribute__((ext_vector_type(16))) float    f32x16;

#define C_IN  256
#define HW_   4096

__global__ __launch_bounds__(256) void prep_w_kernel(
    const float* __restrict__ mat1, const float* __restrict__ Alpha,
    const int* __restrict__ use_alpha, _Float16* __restrict__ Aprep) {
  int t = blockIdx.x * 256 + threadIdx.x;   // o = t&255, c = t>>8
  int o = t & 255;
  int c = t >> 8;
  int ua = use_alpha[0];
  const float* src = mat1 + ((size_t)o * C_IN + c) * 8;
  half8 v;
#pragma unroll
  for (int r = 0; r < 8; ++r) {
    float s = ua ? Alpha[r] : 1.0f;
    v[r] = (_Float16)(src[r] * s);
  }
  // layout: slot (c*256 + o) holds 8 fp16 (r fastest)
  *(half8*)(Aprep + ((size_t)c * 256 + o) * 8) = v;
}

__global__ __launch_bounds__(256, 2) void gemm_deform_kernel(
    const float* __restrict__ mat0, const _Float16* __restrict__ Aprep,
    const float* __restrict__ mask, float* __restrict__ out) {
  // slab = one round: slot = cq*128 + (o-o0), cq 0..7, 16B slots
  __shared__ half8 A_lds[4][1024];   // 64 KiB, 4-slab ring (slab = rd%4)

  int bid = blockIdx.x;
  int wg = (bid & 7) * 64 + (bid >> 3);   // XCD swizzle (512%8==0, bijective)
  int tile_m = wg & 1;                    // M fastest: pair shares mat0 cols
  int tile_n = wg >> 1;                   // 0..255
  int o0 = tile_m * 128;
  int n0 = tile_n * 128;
  int b  = n0 >> 12;
  int p0 = n0 & 4095;

  int t    = threadIdx.x;   // 0..255
  int lane = t & 63;
  int w    = t >> 6;        // 0..3 = M-group (32 rows each); full 128-col N
  int l31  = lane & 31;
  int cr   = lane >> 5;     // c-plane parity within MFMA K=16

  // lane-resident packed fp16 mask for the 4 col-groups
  int colb = p0 + l31;
  half8 mkh[4];
#pragma unroll
  for (int nc = 0; nc < 4; ++nc)
#pragma unroll
    for (int r = 0; r < 8; ++r)
      mkh[nc][r] = (_Float16)mask[r * HW_ + colb + nc * 32];

  // ---- pointer-bump state ----
  const __attribute__((address_space(1))) uint32_t* gA =
      (const __attribute__((address_space(1))) uint32_t*)Aprep;
  __attribute__((address_space(3))) uint32_t* lA =
      (__attribute__((address_space(3))) uint32_t*)&A_lds[0][0];
  // thread stages cq = 2i + (t>>7), row = o0 + (t&127) for i = 0..3.
  // LDS slot within slab = cq*128 + row-off = i*256 + t  (since
  // (2i+(t>>7))*128 + (t&127) = i*256 + t).
  int scq  = t >> 7;        // c-plane parity this thread stages
  int srow = t & 127;       // A-row within tile this thread stages
  // stage pointers (dword units); +8192 dwords (one round = 16KB) per round
  const __attribute__((address_space(1))) uint32_t* gS0 =
      gA + (size_t)((0 + scq) * 256 + o0 + srow) * 4;
  const __attribute__((address_space(1))) uint32_t* gS1 =
      gA + (size_t)((2 + scq) * 256 + o0 + srow) * 4;
  const __attribute__((address_space(1))) uint32_t* gS2 =
      gA + (size_t)((4 + scq) * 256 + o0 + srow) * 4;
  const __attribute__((address_space(1))) uint32_t* gS3 =
      gA + (size_t)((6 + scq) * 256 + o0 + srow) * 4;

  // P pointers kq=0..3 (plane c = rd*8 + kq*2 + cr, column colb + nc*32)
  const float* __restrict__ m0b =
      mat0 + ((size_t)b * C_IN + cr) * HW_ + colb;
  const float* pP0 = m0b + (size_t)0 * HW_;
  const float* pP1 = m0b + (size_t)2 * HW_;
  const float* pP2 = m0b + (size_t)4 * HW_;
  const float* pP3 = m0b + (size_t)6 * HW_;

#define STAGE(SLAB, SB) do {                                                  \
    __builtin_amdgcn_global_load_lds(gS0, lA + (size_t)((SLAB)*1024 + t) * 4,       16, 0, 0); \
    __builtin_amdgcn_global_load_lds(gS1, lA + (size_t)((SLAB)*1024 + 256 + t) * 4, 16, 0, 0); \
    __builtin_amdgcn_global_load_lds(gS2, lA + (size_t)((SLAB)*1024 + 512 + t) * 4, 16, 0, 0); \
    __builtin_amdgcn_global_load_lds(gS3, lA + (size_t)((SLAB)*1024 + 768 + t) * 4, 16, 0, 0); \
    gS0 += (SB); gS1 += (SB); gS2 += (SB); gS3 += (SB);                       \
  } while (0)

  f32x16 acc[4];   // [nc]
#pragma unroll
  for (int nc = 0; nc < 4; ++nc)
#pragma unroll
    for (int j = 0; j < 16; ++j) acc[nc][j] = 0.f;

  float Pev[4][4], Pod[4][4];   // [kq][nc], even/odd round sets

  auto SMk = [&](const float (&Pk)[4], half8 A) {
#pragma unroll
    for (int nc = 0; nc < 4; ++nc) {
      _Float16 h = (_Float16)Pk[nc];
      half8 pb = {h, h, h, h, h, h, h, h};
      half8 bv = pb * mkh[nc];   // 4x v_pk_mul_f16
      acc[nc] = __builtin_amdgcn_mfma_f32_32x32x16_f16(A, bv, acc[nc], 0, 0, 0);
    }
  };

  int abase = w * 32 + l31;   // A-frag row; + (kq*2+cr)*128

  // COMP one round from slab Ab; read-ahead next kq's frag; refill P (+PB)
  auto COMP = [&](const half8* __restrict__ Ab, float (&P)[4][4], int PB) {
    half8 a0 = Ab[(0 + cr) * 128 + abase];
    half8 a1 = Ab[(2 + cr) * 128 + abase];
    SMk(P[0], a0);
    P[0][0] = pP0[0]; P[0][1] = pP0[32]; P[0][2] = pP0[64]; P[0][3] = pP0[96];
    pP0 += PB;
    a0 = Ab[(4 + cr) * 128 + abase];
    SMk(P[1], a1);
    P[1][0] = pP1[0]; P[1][1] = pP1[32]; P[1][2] = pP1[64]; P[1][3] = pP1[96];
    pP1 += PB;
    a1 = Ab[(6 + cr) * 128 + abase];
    SMk(P[2], a0);
    P[2][0] = pP2[0]; P[2][1] = pP2[32]; P[2][2] = pP2[64]; P[2][3] = pP2[96];
    pP2 += PB;
    SMk(P[3], a1);
    P[3][0] = pP3[0]; P[3][1] = pP3[32]; P[3][2] = pP3[64]; P[3][3] = pP3[96];
    pP3 += PB;
  };

  auto LOADP = [&](float (&P)[4][4]) {   // prologue only; bumps one round
    P[0][0] = pP0[0]; P[0][1] = pP0[32]; P[0][2] = pP0[64]; P[0][3] = pP0[96];
    P[1][0] = pP1[0]; P[1][1] = pP1[32]; P[1][2] = pP1[64]; P[1][3] = pP1[96];
    P[2][0] = pP2[0]; P[2][1] = pP2[32]; P[2][2] = pP2[64]; P[2][3] = pP2[96];
    P[3][0] = pP3[0]; P[3][1] = pP3[32]; P[3][2] = pP3[64]; P[3][3] = pP3[96];
    pP0 += 8 * HW_; pP1 += 8 * HW_; pP2 += 8 * HW_; pP3 += 8 * HW_;
  };

  // ---- prologue: stage rounds 0,1 (slabs 0,1); load P rounds 0,1 ----
  STAGE(0, 8192);
  STAGE(1, 8192);
  LOADP(Pev);
  LOADP(Pod);
  // stage + P pointers now at round 2

  // ---- main loop: 4 rounds/iter; vmcnt(0) + barrier every 2 rounds ----
#pragma unroll 1
  for (int g = 0; g < 8; ++g) {
    int rd = g * 4;
    // rounds rd, rd+1 (slabs 0,1); stage rd+2, rd+3 (slabs 2,3)
    asm volatile("s_waitcnt vmcnt(0)" ::: "memory");   // order-robust drain
    __builtin_amdgcn_s_barrier();                      // all waves past rd-1
    {
      int sb2 = (rd + 2 < 31) ? 8192 : 0;
      int sb3 = (rd + 3 < 31) ? 8192 : 0;
      int pb2 = (rd + 2 < 31) ? 8 * HW_ : 0;
      int pb3 = (rd + 3 < 31) ? 8 * HW_ : 0;
      STAGE(2, sb2);
      STAGE(3, sb3);
      COMP(&A_lds[0][0], Pev, pb2);
      COMP(&A_lds[1][0], Pod, pb3);
    }
    // rounds rd+2, rd+3 (slabs 2,3); stage rd+4, rd+5 (slabs 0,1)
    asm volatile("s_waitcnt vmcnt(0)" ::: "memory");
    __builtin_amdgcn_s_barrier();
    {
      int sb4 = (rd + 4 < 31) ? 8192 : 0;
      int sb5 = (rd + 5 < 31) ? 8192 : 0;
      int pb4 = (rd + 4 < 31) ? 8 * HW_ : 0;
      int pb5 = (rd + 5 < 31) ? 8 * HW_ : 0;
      STAGE(0, sb4);
      STAGE(1, sb5);
      COMP(&A_lds[2][0], Pev, pb4);
      COMP(&A_lds[3][0], Pod, pb5);
    }
  }

  // ---- epilogue: 32x32 C/D layout col=lane&31, row=(reg&3)+8*(reg>>2)+4*cr ----
  size_t obase = (size_t)b * 256 * HW_ + colb;
#pragma unroll
  for (int nc = 0; nc < 4; ++nc) {
#pragma unroll
    for (int reg = 0; reg < 16; ++reg) {
      int row = o0 + w * 32 + (reg & 3) + 8 * (reg >> 2) + 4 * cr;
      out[obase + (size_t)row * HW_ + nc * 32] = acc[nc][reg];
    }
  }
}

extern "C" void kernel_launch(void* const* d_in, const int* in_sizes, int n_in,
                              void* d_out, int out_size, void* d_ws, size_t ws_size,
                              hipStream_t stream) {
  const float* mat0      = (const float*)d_in[0];   // [8,256,64,64]
  const float* mat1      = (const float*)d_in[1];   // [256,256,8]
  const float* mask      = (const float*)d_in[2];   // [8,64,64]
  const float* Alpha     = (const float*)d_in[3];   // [8]
  const int*   use_alpha = (const int*)d_in[4];     // [1]
  (void)in_sizes; (void)n_in; (void)out_size; (void)ws_size;

  _Float16* Aprep = (_Float16*)d_ws;                // 1 MiB scratch
  float* outp  = (float*)d_out;

  prep_w_kernel<<<256, 256, 0, stream>>>(mat1, Alpha, use_alpha, Aprep);
  gemm_deform_kernel<<<512, 256, 0, stream>>>(mat0, Aprep, mask, outp);
}

// Round 19
// 47.540 us; speedup vs baseline: 1.0936x; 1.0936x over previous
//
#include <hip/hip_runtime.h>
#include <hip/hip_bf16.h>
#include <stdint.h>

// out[b,o,p] = sum_{r,c} mat0[b,c,p] * mat1[o,c,r]*Alpha[r] * mask[r,p]
// GEMM: M=256 (o), N=32768 (n=b*4096+p), K=2048 (k=c*8+r).
// A[o,k] = mat1[o,c,r]*Alpha[r]  (prepped FP16 in d_ws, layout [c][o][8r])
// B[k,n] = mat0[b,c,p]*mask[r,p] synthesized IN REGISTERS per lane (fp16).
// Round 19 = R14 restored (best measured: 43.9-44.5 us, 781 TF effective =
// 87% of the m97-structure's ~900 TF plain-HIP ceiling; accounting for the
// mandatory ~500 cyc/CU-round B-synth VALU, predicted ceiling ~770 TF ->
// measured 781: the model closes). Structure: 128x128 tile, 4 waves of
// 64x64 (32x32x16 MFMA), 4-slab LDS ring staged via global_load_lds,
// pointer-bump addressing, read-ahead ds_reads, fp16 synth (1 cvt + 4
// v_pk_mul_f16 per fragment), one vmcnt(0)+barrier per 2 rounds.
// Falsified alternatives: 2x occupancy (R15), barrier-free (R10), anti-
// lockstep (R13), per-phase interleave (R11), A-read-once (R18), deeper
// P-cover (R7/R12).

typedef __attribute__((ext_vector_type(8)))  _Float16 half8;
typedef __attribute__((ext_vector_type(16))) float    f32x16;

#define C_IN  256
#define HW_   4096

__global__ __launch_bounds__(256) void prep_w_kernel(
    const float* __restrict__ mat1, const float* __restrict__ Alpha,
    const int* __restrict__ use_alpha, _Float16* __restrict__ Aprep) {
  int t = blockIdx.x * 256 + threadIdx.x;   // o = t&255, c = t>>8
  int o = t & 255;
  int c = t >> 8;
  int ua = use_alpha[0];
  const float* src = mat1 + ((size_t)o * C_IN + c) * 8;
  half8 v;
#pragma unroll
  for (int r = 0; r < 8; ++r) {
    float s = ua ? Alpha[r] : 1.0f;
    v[r] = (_Float16)(src[r] * s);
  }
  // layout: slot (c*256 + o) holds 8 fp16 (r fastest)
  *(half8*)(Aprep + ((size_t)c * 256 + o) * 8) = v;
}

__global__ __launch_bounds__(256, 2) void gemm_deform_kernel(
    const float* __restrict__ mat0, const _Float16* __restrict__ Aprep,
    const float* __restrict__ mask, float* __restrict__ out) {
  // slab = one round: 8 c-planes x 128 rows, slot = cq*128 + (o-o0), 16B
  __shared__ half8 A_lds[4][1024];   // 64 KiB, 4-slab ring (slab = rd%4)

  int bid = blockIdx.x;
  int wg = (bid & 7) * 64 + (bid >> 3);   // XCD swizzle (512%8==0, bijective)
  int tile_m = wg & 1;                    // M fastest: pair shares mat0 cols
  int tile_n = wg >> 1;                   // 0..255
  int o0 = tile_m * 128;
  int n0 = tile_n * 128;
  int b  = n0 >> 12;
  int p0 = n0 & 4095;

  int t    = threadIdx.x;
  int lane = t & 63;
  int w    = t >> 6;        // 0..3
  int wc   = w & 1;         // N-half (64 cols)
  int wr   = w >> 1;        // M-half (64 rows)
  int l31  = lane & 31;
  int cr   = lane >> 5;     // c-plane parity within MFMA K=16

  // lane-resident packed fp16 mask for this wave's two 32-col groups
  int colb = p0 + wc * 64 + l31;
  half8 mkh0, mkh1;
#pragma unroll
  for (int r = 0; r < 8; ++r) {
    mkh0[r] = (_Float16)mask[r * HW_ + colb];
    mkh1[r] = (_Float16)mask[r * HW_ + colb + 32];
  }

  // mat0 scalar base: plane c = rd*8 + kq*2 + cr, columns colb / colb+32
  const float* __restrict__ m0b =
      mat0 + ((size_t)b * C_IN + cr) * HW_ + colb;

  // ---- pointer-bump state ----
  const __attribute__((address_space(1))) uint32_t* gA =
      (const __attribute__((address_space(1))) uint32_t*)Aprep;
  __attribute__((address_space(3))) uint32_t* lA =
      (__attribute__((address_space(3))) uint32_t*)&A_lds[0][0];
  int soo  = (w & 1) * 64 + lane;
  int scqb = w >> 1;
  // stage pointers i=0..3 (dword units); advance 8192 dwords (32KB) / round
  const __attribute__((address_space(1))) uint32_t* gS0 =
      gA + (size_t)((0 * 2 + scqb) * 256 + o0 + soo) * 4;
  const __attribute__((address_space(1))) uint32_t* gS1 =
      gA + (size_t)((1 * 2 + scqb) * 256 + o0 + soo) * 4;
  const __attribute__((address_space(1))) uint32_t* gS2 =
      gA + (size_t)((2 * 2 + scqb) * 256 + o0 + soo) * 4;
  const __attribute__((address_space(1))) uint32_t* gS3 =
      gA + (size_t)((3 * 2 + scqb) * 256 + o0 + soo) * 4;
  // P pointers kq=0..3; advance 8*HW_ floats (128KB) / round
  const float* pP0 = m0b + (size_t)0 * HW_;
  const float* pP1 = m0b + (size_t)2 * HW_;
  const float* pP2 = m0b + (size_t)4 * HW_;
  const float* pP3 = m0b + (size_t)6 * HW_;

#define STAGE(SLAB, SB) do {                                                  \
    __builtin_amdgcn_global_load_lds(gS0, lA + ((SLAB)*1024 + 0*256 + w*64)*4, 16, 0, 0); \
    __builtin_amdgcn_global_load_lds(gS1, lA + ((SLAB)*1024 + 1*256 + w*64)*4, 16, 0, 0); \
    __builtin_amdgcn_global_load_lds(gS2, lA + ((SLAB)*1024 + 2*256 + w*64)*4, 16, 0, 0); \
    __builtin_amdgcn_global_load_lds(gS3, lA + ((SLAB)*1024 + 3*256 + w*64)*4, 16, 0, 0); \
    gS0 += (SB); gS1 += (SB); gS2 += (SB); gS3 += (SB);                       \
  } while (0)

  f32x16 acc00, acc01, acc10, acc11;
#pragma unroll
  for (int j = 0; j < 16; ++j) { acc00[j] = 0.f; acc01[j] = 0.f; acc10[j] = 0.f; acc11[j] = 0.f; }

  float Pev[4][2], Pod[4][2];   // P sets for even / odd rounds

  auto SM = [&](float s0, float s1, half8 A0, half8 A1) {
    _Float16 h0 = (_Float16)s0, h1 = (_Float16)s1;
    half8 pb0 = {h0, h0, h0, h0, h0, h0, h0, h0};
    half8 pb1 = {h1, h1, h1, h1, h1, h1, h1, h1};
    half8 bv0 = pb0 * mkh0;   // 4x v_pk_mul_f16
    half8 bv1 = pb1 * mkh1;
    acc00 = __builtin_amdgcn_mfma_f32_32x32x16_f16(A0, bv0, acc00, 0, 0, 0);
    acc01 = __builtin_amdgcn_mfma_f32_32x32x16_f16(A0, bv1, acc01, 0, 0, 0);
    acc10 = __builtin_amdgcn_mfma_f32_32x32x16_f16(A1, bv0, acc10, 0, 0, 0);
    acc11 = __builtin_amdgcn_mfma_f32_32x32x16_f16(A1, bv1, acc11, 0, 0, 0);
  };

  int abase = wr * 64 + l31;   // + (kq*2+cr)*128 (+32 for second frag)

  // COMP one round from slab Ab using P set; refills P (next-next round)
  auto COMP = [&](const half8* __restrict__ Ab, float (&P)[4][2], int PB) {
    half8 a0 = Ab[(0 + cr) * 128 + abase];
    half8 a1 = Ab[(0 + cr) * 128 + abase + 32];
    // phase 0: read kq1 ahead, compute kq0, refill P0
    half8 b0 = Ab[(2 + cr) * 128 + abase];
    half8 b1 = Ab[(2 + cr) * 128 + abase + 32];
    SM(P[0][0], P[0][1], a0, a1);
    P[0][0] = pP0[0]; P[0][1] = pP0[32]; pP0 += PB;
    // phase 1: read kq2 ahead, compute kq1, refill P1
    a0 = Ab[(4 + cr) * 128 + abase];
    a1 = Ab[(4 + cr) * 128 + abase + 32];
    SM(P[1][0], P[1][1], b0, b1);
    P[1][0] = pP1[0]; P[1][1] = pP1[32]; pP1 += PB;
    // phase 2: read kq3 ahead, compute kq2, refill P2
    b0 = Ab[(6 + cr) * 128 + abase];
    b1 = Ab[(6 + cr) * 128 + abase + 32];
    SM(P[2][0], P[2][1], a0, a1);
    P[2][0] = pP2[0]; P[2][1] = pP2[32]; pP2 += PB;
    // phase 3: compute kq3, refill P3
    SM(P[3][0], P[3][1], b0, b1);
    P[3][0] = pP3[0]; P[3][1] = pP3[32]; pP3 += PB;
  };

  // ---- prologue: stage rounds 0,1 (slabs 0,1); load P rounds 0,1 ----
  STAGE(0, 8192);
  STAGE(1, 8192);
  Pev[0][0] = pP0[0]; Pev[0][1] = pP0[32]; pP0 += 8 * HW_;
  Pev[1][0] = pP1[0]; Pev[1][1] = pP1[32]; pP1 += 8 * HW_;
  Pev[2][0] = pP2[0]; Pev[2][1] = pP2[32]; pP2 += 8 * HW_;
  Pev[3][0] = pP3[0]; Pev[3][1] = pP3[32]; pP3 += 8 * HW_;
  Pod[0][0] = pP0[0]; Pod[0][1] = pP0[32]; pP0 += 8 * HW_;
  Pod[1][0] = pP1[0]; Pod[1][1] = pP1[32]; pP1 += 8 * HW_;
  Pod[2][0] = pP2[0]; Pod[2][1] = pP2[32]; pP2 += 8 * HW_;
  Pod[3][0] = pP3[0]; Pod[3][1] = pP3[32]; pP3 += 8 * HW_;
  // pointers now at round 2 (stage and P)

  // ---- main loop: 4 rounds per iter; barrier+vmcnt every 2 rounds ----
#pragma unroll 1
  for (int g = 0; g < 8; ++g) {
    int rd = g * 4;
    // rounds rd, rd+1 (slabs 0,1); stage rd+2, rd+3 (slabs 2,3)
    asm volatile("s_waitcnt vmcnt(0)" ::: "memory");   // 2-round-old loads
    __builtin_amdgcn_s_barrier();                      // all waves past rd-1
    {
      int sb2 = (rd + 2 < 31) ? 8192 : 0;
      int sb3 = (rd + 3 < 31) ? 8192 : 0;
      int pb2 = (rd + 2 < 31) ? 8 * HW_ : 0;
      int pb3 = (rd + 3 < 31) ? 8 * HW_ : 0;
      STAGE(2, sb2);
      STAGE(3, sb3);
      COMP(&A_lds[0][0], Pev, pb2);
      COMP(&A_lds[1][0], Pod, pb3);
    }
    // rounds rd+2, rd+3 (slabs 2,3); stage rd+4, rd+5 (slabs 0,1)
    asm volatile("s_waitcnt vmcnt(0)" ::: "memory");
    __builtin_amdgcn_s_barrier();
    {
      int sb4 = (rd + 4 < 31) ? 8192 : 0;
      int sb5 = (rd + 5 < 31) ? 8192 : 0;
      int pb4 = (rd + 4 < 31) ? 8 * HW_ : 0;
      int pb5 = (rd + 5 < 31) ? 8 * HW_ : 0;
      STAGE(0, sb4);
      STAGE(1, sb5);
      COMP(&A_lds[2][0], Pev, pb4);
      COMP(&A_lds[3][0], Pod, pb5);
    }
  }

  // ---- epilogue: 32x32 C/D layout col=lane&31, row=(reg&3)+8*(reg>>2)+4*cr ----
  size_t obase = (size_t)b * 256 * HW_ + colb;
#pragma unroll
  for (int reg = 0; reg < 16; ++reg) {
    int row = o0 + wr * 64 + (reg & 3) + 8 * (reg >> 2) + 4 * cr;
    out[obase + (size_t)row * HW_]                    = acc00[reg];
    out[obase + (size_t)row * HW_ + 32]               = acc01[reg];
    out[obase + (size_t)(row + 32) * HW_]             = acc10[reg];
    out[obase + (size_t)(row + 32) * HW_ + 32]        = acc11[reg];
  }
}

extern "C" void kernel_launch(void* const* d_in, const int* in_sizes, int n_in,
                              void* d_out, int out_size, void* d_ws, size_t ws_size,
                              hipStream_t stream) {
  const float* mat0      = (const float*)d_in[0];   // [8,256,64,64]
  const float* mat1      = (const float*)d_in[1];   // [256,256,8]
  const float* mask      = (const float*)d_in[2];   // [8,64,64]
  const float* Alpha     = (const float*)d_in[3];   // [8]
  const int*   use_alpha = (const int*)d_in[4];     // [1]
  (void)in_sizes; (void)n_in; (void)out_size; (void)ws_size;

  _Float16* Aprep = (_Float16*)d_ws;                // 1 MiB scratch
  float* outp  = (float*)d_out;

  prep_w_kernel<<<256, 256, 0, stream>>>(mat1, Alpha, use_alpha, Aprep);
  gemm_deform_kernel<<<512, 256, 0, stream>>>(mat0, Aprep, mask, outp);
}